// Round 1
// baseline (67.649 us; speedup 1.0000x reference)
//
#include <hip/hip_runtime.h>

#define N_ELEM (1 << 20)
#define K 256
#define BLOCK 256
#define EPT 4
#define GRID (N_ELEM / (BLOCK * EPT))   // 1024 blocks -> 4 blocks/CU, 16 waves/CU

// dur_us floor: ~63 us is harness re-poison (268 MB ws fill at ~41 us, 82% HBM peak).
// Kernel-side budget ~4.6 us; this revision attacks its LDS bank conflicts:
//   - binary-search probes at s=8/4/2/1 hit only 4/8/16 of 32 banks (pos is a
//     multiple of 2s) -> XOR-swizzle s_val[i ^ (i>>5)] makes every level's
//     probe set land in distinct banks.
//   - top 4 levels (s=128..16) need only the 15 values A[16i+15] -> exported
//     to ws_top by the sort kernel, resolved in registers (cndmask tree).
//     LDS probes per element: 9 -> 5; dependent-chain length: 9 -> 5.
//   - sort kernel scan: 256 x ds_read_b32 -> 64 x ds_read_b128 broadcasts.
// Math is bit-identical to the R2 kernel (same values, same compares, same
// tie rule) -> absmax must stay 0.

// d_ws layout: float sorted_val[256] | int sorted_orig_idx[256] | float top[16]

__global__ __launch_bounds__(K) void sort_centers_kernel(
    const float* __restrict__ centers,
    float* __restrict__ ws_val,
    int*   __restrict__ ws_idx,
    float* __restrict__ ws_top)
{
    __shared__ __align__(16) float sc[K];
    const int t = threadIdx.x;
    const float c = centers[t];
    sc[t] = c;
    __syncthreads();

    // Rank sort, stable (ties by original index). float4 broadcasts: 64 LDS ops.
    int rank = 0;
    const float4* sc4 = reinterpret_cast<const float4*>(sc);
#pragma unroll 8
    for (int q = 0; q < K / 4; ++q) {
        const float4 v = sc4[q];
        const int j = q * 4;
        rank += (v.x < c) || (v.x == c && (j + 0) < t);
        rank += (v.y < c) || (v.y == c && (j + 1) < t);
        rank += (v.z < c) || (v.z == c && (j + 2) < t);
        rank += (v.w < c) || (v.w == c && (j + 3) < t);
    }
    ws_val[rank] = c;
    ws_idx[rank] = t;
    // Export A[15], A[31], ..., A[239] as ws_top[0..14] (rank 255 -> slot 15, unused).
    if ((rank & 15) == 15) ws_top[rank >> 4] = c;
}

__global__ __launch_bounds__(BLOCK) void argmin_bsearch_kernel(
    const float* __restrict__ x,
    const float* __restrict__ ws_val,
    const int*   __restrict__ ws_idx,
    const float* __restrict__ ws_top,
    int*         __restrict__ out)
{
    // s_val is bank-deswizzled: value of rank i lives at s_val[i ^ (i>>5)].
    // sigma(i) = i ^ (i>>5) is a bijection on [0,256) (per-32 block permutation)
    // and spreads each probe level's address set across distinct banks.
    __shared__ float s_val[K];
    __shared__ int   s_idx[K];
    const int t = threadIdx.x;
    s_val[t ^ (t >> 5)] = ws_val[t];   // write banks: (t&31)^(t>>5) -> 2-way, free
    s_idx[t] = ws_idx[t];

    // Top-of-tree values A[16i+15], uniform addresses -> loaded once.
    // tA = A[15,31,47,63], tB = A[79,95,111,127], tC = A[143,159,175,191],
    // tD = A[207,223,239,-].
    const float4 tA = *reinterpret_cast<const float4*>(ws_top + 0);
    const float4 tB = *reinterpret_cast<const float4*>(ws_top + 4);
    const float4 tC = *reinterpret_cast<const float4*>(ws_top + 8);
    const float4 tD = *reinterpret_cast<const float4*>(ws_top + 12);
    __syncthreads();

    const int base = (blockIdx.x * BLOCK + t) * EPT;
    const float4 v = *reinterpret_cast<const float4*>(x + base);
    float xs[EPT] = {v.x, v.y, v.z, v.w};
    int res[EPT];

#pragma unroll
    for (int e = 0; e < EPT; ++e) {
        const float xv = xs[e];

        // Levels s=128,64,32,16 in registers (same compares as LDS version).
        const bool c1 = tB.w < xv;                      // A[127]
        const float v2 = c1 ? tC.w : tA.w;              // A[191] : A[63]
        const bool c2 = v2 < xv;
        const float v3 = c1 ? (c2 ? tD.y : tC.y)        // A[223] : A[159]
                            : (c2 ? tB.y : tA.y);       // A[95]  : A[31]
        const bool c3 = v3 < xv;
        const float v4 = c1 ? (c2 ? (c3 ? tD.z : tD.x)  // A[239] : A[207]
                                  : (c3 ? tC.z : tC.x)) // A[175] : A[143]
                            : (c2 ? (c3 ? tB.z : tB.x)  // A[111] : A[79]
                                  : (c3 ? tA.z : tA.x));// A[47]  : A[15]
        const bool c4 = v4 < xv;
        int pos = ((((((int)c1 << 1) | (int)c2) << 1 | (int)c3) << 1) | (int)c4) << 4;

        // Levels s=8,4,2,1: swizzled probes -> distinct banks at every level.
#pragma unroll
        for (int s = 8; s > 0; s >>= 1) {
            const int p = pos + s - 1;
            pos += (s_val[p ^ (p >> 5)] < xv) ? s : 0;
        }
        {   // final lower_bound correction; pos in [0,256] after this
            const int p = pos;
            pos += (s_val[p ^ (p >> 5)] < xv) ? 1 : 0;
        }

        // Nearest is one of the two straddling neighbors; exact tie -> smaller
        // original index (identical to R2 kernel).
        const int il = (pos > 0) ? pos - 1 : 0;
        const int ir = (pos < K) ? pos : K - 1;
        const float dl = fabsf(xv - s_val[il ^ (il >> 5)]);
        const float dr = fabsf(xv - s_val[ir ^ (ir >> 5)]);
        const int ol = s_idx[il], orr = s_idx[ir];
        res[e] = (dl < dr) ? ol : ((dr < dl) ? orr : min(ol, orr));
    }

    *reinterpret_cast<int4*>(out + base) = make_int4(res[0], res[1], res[2], res[3]);
}

extern "C" void kernel_launch(void* const* d_in, const int* in_sizes, int n_in,
                              void* d_out, int out_size, void* d_ws, size_t ws_size,
                              hipStream_t stream)
{
    const float* x       = (const float*)d_in[0];
    const float* centers = (const float*)d_in[1];
    int*         out     = (int*)d_out;

    float* ws_val = (float*)d_ws;
    int*   ws_idx = (int*)(ws_val + K);
    float* ws_top = (float*)(ws_idx + K);

    sort_centers_kernel<<<1, K, 0, stream>>>(centers, ws_val, ws_idx, ws_top);
    argmin_bsearch_kernel<<<GRID, BLOCK, 0, stream>>>(x, ws_val, ws_idx, ws_top, out);
}